// Round 1
// baseline (1769.294 us; speedup 1.0000x reference)
//
#include <hip/hip_runtime.h>
#include <hip/hip_bf16.h>

// SVD-RNN: W = U diag(s) V from Householder chains; h_t = tanh(xp_t + W h_{t-1});
// out_t = h_t W_out^T + b_out.
// Sizes fixed by the reference:
#define BB 64
#define TT 2048
#define II 128
#define HH 256
#define OO 128

__device__ __forceinline__ float bfu2f(unsigned int v) {
    return __uint_as_float(v << 16);
}

__device__ __forceinline__ float tanh_fast(float x) {
    // tanh(x) = (e^{2x}-1)/(e^{2x}+1), clamped to avoid inf/inf
    float xc = fminf(fmaxf(x, -9.0f), 9.0f);
    float e = __expf(2.0f * xc);
    return (e - 1.0f) * __fdividef(1.0f, e + 1.0f);
}

// ---------------------------------------------------------------------------
// Kernel 1: build effective (masked+flipped) Householder vectors and betas.
// u_eff[i][c] = u_raw[i][255-c] for c >= 255-i else 0       (flip axis=1)
// v_eff[i][c] = v_raw[255-i][255-c] for c >= i else 0       (flip axes 0,1)
// beta = 2 / <vec,vec>
// grid: 512 blocks (256 U rows + 256 V rows) x 64 threads (1 wave)
// ---------------------------------------------------------------------------
__global__ __launch_bounds__(64) void prep_kernel(
    const float* __restrict__ u_raw, const float* __restrict__ v_raw,
    float* __restrict__ u_eff, float* __restrict__ v_eff,
    float* __restrict__ beta_u, float* __restrict__ beta_v)
{
    const int row = blockIdx.x;
    const int lane = threadIdx.x;
    const bool isU = row < HH;
    const int i = isU ? row : row - HH;
    const float* src = isU ? (u_raw + (size_t)i * HH) : (v_raw + (size_t)(HH - 1 - i) * HH);
    float* dst = (isU ? u_eff : v_eff) + (size_t)i * HH;
    const int lo = isU ? (HH - 1 - i) : i;   // nonzero region: c >= lo
    float ss = 0.0f;
    for (int c = lane; c < HH; c += 64) {
        float vv = (c >= lo) ? src[HH - 1 - c] : 0.0f;
        dst[c] = vv;
        ss += vv * vv;
    }
    for (int m = 1; m < 64; m <<= 1) ss += __shfl_xor(ss, m, 64);
    if (lane == 0) (isU ? beta_u : beta_v)[i] = 2.0f / ss;
}

// ---------------------------------------------------------------------------
// Kernel 2: Householder chain applied per column: c <- c - beta*(v.c)*v.
// One wave per column; lane l holds rows 4l..4l+3 of the column.
// Stores Ucol[k*256 + r] = U[r][k] (column-contiguous) and
//        Vrow[k*256 + c] = V[k][c] (row-contiguous, transposed store).
// grid: 128 blocks x 256 threads (4 waves/block, 512 columns total)
// ---------------------------------------------------------------------------
__global__ __launch_bounds__(256) void hh_kernel(
    const float* __restrict__ u_eff, const float* __restrict__ v_eff,
    const float* __restrict__ beta_u, const float* __restrict__ beta_v,
    float* __restrict__ Ucol, float* __restrict__ Vrow)
{
    const int wid = blockIdx.x * 4 + (threadIdx.x >> 6);
    const int lane = threadIdx.x & 63;
    const bool isU = wid < HH;
    const int j = isU ? wid : wid - HH;
    const float* eff = isU ? u_eff : v_eff;
    const float* beta = isU ? beta_u : beta_v;

    float cr0 = (j == 4 * lane + 0) ? 1.0f : 0.0f;
    float cr1 = (j == 4 * lane + 1) ? 1.0f : 0.0f;
    float cr2 = (j == 4 * lane + 2) ? 1.0f : 0.0f;
    float cr3 = (j == 4 * lane + 3) ? 1.0f : 0.0f;

    // For U, reflector i touches only rows >= 255-i; column j (initially e_j)
    // is first touched at i = 255-j. For V, reflector 0 already has full support.
    const int i0 = isU ? (HH - 1 - j) : 0;
    for (int i = i0; i < HH; ++i) {
        const float4 v4 = *(const float4*)(eff + (size_t)i * HH + lane * 4);
        float d = v4.x * cr0 + v4.y * cr1 + v4.z * cr2 + v4.w * cr3;
        for (int m = 1; m < 64; m <<= 1) d += __shfl_xor(d, m, 64);
        const float t = beta[i] * d;
        cr0 = fmaf(-t, v4.x, cr0);
        cr1 = fmaf(-t, v4.y, cr1);
        cr2 = fmaf(-t, v4.z, cr2);
        cr3 = fmaf(-t, v4.w, cr3);
    }
    if (isU) {
        float4 o = make_float4(cr0, cr1, cr2, cr3);
        *(float4*)(Ucol + (size_t)j * HH + lane * 4) = o;
    } else {
        Vrow[(size_t)(4 * lane + 0) * HH + j] = cr0;
        Vrow[(size_t)(4 * lane + 1) * HH + j] = cr1;
        Vrow[(size_t)(4 * lane + 2) * HH + j] = cr2;
        Vrow[(size_t)(4 * lane + 3) * HH + j] = cr3;
    }
}

// ---------------------------------------------------------------------------
// Kernel 3: W[r][c] = sum_k Ucol[k][r] * sig[k] * Vrow[k][c]
// grid: 256 blocks (r) x 256 threads (c). Ucol/sig loads are wave-uniform
// (scalar loads); Vrow loads coalesced.
// ---------------------------------------------------------------------------
__global__ __launch_bounds__(256) void w_kernel(
    const float* __restrict__ Ucol, const float* __restrict__ Vrow,
    const float* __restrict__ sig, float* __restrict__ Wm)
{
    const int r = blockIdx.x;
    const int c = threadIdx.x;
    float acc = 0.0f;
    #pragma unroll 4
    for (int k = 0; k < HH; ++k) {
        acc = fmaf(Ucol[(size_t)k * HH + r] * sig[k], Vrow[(size_t)k * HH + c], acc);
    }
    Wm[(size_t)r * HH + c] = acc;
}

// ---------------------------------------------------------------------------
// Generic tiled GEMM with bias: C[M][N] = A[M][K] * B[N][K]^T + bias[N]
// BM=BN=64, BK=32, 256 threads, 4x4 micro-tile (n strided by 16 for
// bank-friendly Bs reads). AT in {float, bf16}, OT in {float, bf16}.
// ---------------------------------------------------------------------------
__device__ __forceinline__ void load8f(float* dst, const float* p) {
    float4 a = *(const float4*)p;
    float4 b = *(const float4*)(p + 4);
    dst[0] = a.x; dst[1] = a.y; dst[2] = a.z; dst[3] = a.w;
    dst[4] = b.x; dst[5] = b.y; dst[6] = b.z; dst[7] = b.w;
}
__device__ __forceinline__ void load8f(float* dst, const __hip_bfloat16* p) {
    uint4 u = *(const uint4*)p;
    dst[0] = bfu2f(u.x & 0xffffu); dst[1] = bfu2f(u.x >> 16);
    dst[2] = bfu2f(u.y & 0xffffu); dst[3] = bfu2f(u.y >> 16);
    dst[4] = bfu2f(u.z & 0xffffu); dst[5] = bfu2f(u.z >> 16);
    dst[6] = bfu2f(u.w & 0xffffu); dst[7] = bfu2f(u.w >> 16);
}
__device__ __forceinline__ void storeC(float* p, float v) { *p = v; }
__device__ __forceinline__ void storeC(__hip_bfloat16* p, float v) { *p = __float2bfloat16(v); }

template <typename AT, typename OT>
__global__ __launch_bounds__(256) void gemm_bias(
    const AT* __restrict__ A, const float* __restrict__ Bm,
    const float* __restrict__ bias, OT* __restrict__ C,
    int M, int N, int K)
{
    __shared__ float As[64][36];   // stride 36 floats = 144B, 16B-aligned rows
    __shared__ float Bs[64][36];
    const int m0 = blockIdx.x * 64;
    const int n0 = blockIdx.y * 64;
    const int tid = threadIdx.x;
    const int lr = tid >> 2;            // load row 0..63
    const int lc = (tid & 3) << 3;      // load col offset 0,8,16,24
    const int tm = tid >> 4;            // 0..15
    const int tn = tid & 15;            // 0..15
    float acc[4][4] = {};
    for (int k0 = 0; k0 < K; k0 += 32) {
        load8f(&As[lr][lc], A + (size_t)(m0 + lr) * K + k0 + lc);
        load8f(&Bs[lr][lc], Bm + (size_t)(n0 + lr) * K + k0 + lc);
        __syncthreads();
        #pragma unroll
        for (int k4 = 0; k4 < 32; k4 += 4) {
            float4 a4[4], b4[4];
            #pragma unroll
            for (int r = 0; r < 4; ++r) {
                a4[r] = *(const float4*)&As[tm * 4 + r][k4];
                b4[r] = *(const float4*)&Bs[tn + 16 * r][k4];
            }
            #pragma unroll
            for (int i2 = 0; i2 < 4; ++i2) {
                #pragma unroll
                for (int j2 = 0; j2 < 4; ++j2) {
                    acc[i2][j2] = fmaf(a4[i2].x, b4[j2].x, acc[i2][j2]);
                    acc[i2][j2] = fmaf(a4[i2].y, b4[j2].y, acc[i2][j2]);
                    acc[i2][j2] = fmaf(a4[i2].z, b4[j2].z, acc[i2][j2]);
                    acc[i2][j2] = fmaf(a4[i2].w, b4[j2].w, acc[i2][j2]);
                }
            }
        }
        __syncthreads();
    }
    #pragma unroll
    for (int j2 = 0; j2 < 4; ++j2) {
        const int n = n0 + tn + 16 * j2;
        const float bv = bias[n];
        #pragma unroll
        for (int i2 = 0; i2 < 4; ++i2) {
            const int m = m0 + tm * 4 + i2;
            storeC(C + (size_t)m * N + n, acc[i2][j2] + bv);
        }
    }
}

// ---------------------------------------------------------------------------
// Kernel 5: the sequential recurrence. One workgroup per batch element.
// 1024 threads: g = tid&63 -> output group j = 4g..4g+3; q = tid>>6 (= wave id)
// -> k-slice q*16..+16. W held in registers (64 f32/thread). Per step:
//   phase1: acc[jj] = sum_k W[j][k] h[k]   (h read as wave-uniform LDS b128)
//   -> ps[q][j]; barrier; phase2 (tid<256): reduce 16 partials + xp, tanh,
//   write h to LDS double-buffer + bf16 h_all to global; barrier.
// xp is prefetched one step ahead so the global load latency hides in phase1.
// ---------------------------------------------------------------------------
__global__ __launch_bounds__(1024, 1) void recur_kernel(
    const float* __restrict__ Wm,                 // [256][256] row-major
    const __hip_bfloat16* __restrict__ xp,        // [B][T][256]
    __hip_bfloat16* __restrict__ hall)            // [B][T][256]
{
    const int b = blockIdx.x;
    const int tid = threadIdx.x;
    const int g = tid & 63;
    const int q = tid >> 6;
    __shared__ float hbuf[2][HH];
    __shared__ float ps[16][HH];

    // Load W fragment: rows 4g..4g+3, cols q*16..q*16+15
    float w[4][16];
    const float* Wp = Wm + (size_t)(g * 4) * HH + q * 16;
    #pragma unroll
    for (int jj = 0; jj < 4; ++jj) {
        #pragma unroll
        for (int c4 = 0; c4 < 4; ++c4) {
            float4 t4 = *(const float4*)(Wp + (size_t)jj * HH + c4 * 4);
            w[jj][c4 * 4 + 0] = t4.x;
            w[jj][c4 * 4 + 1] = t4.y;
            w[jj][c4 * 4 + 2] = t4.z;
            w[jj][c4 * 4 + 3] = t4.w;
        }
    }
    if (tid < HH) hbuf[0][tid] = 0.0f;
    __syncthreads();

    const __hip_bfloat16* xpb = xp + (size_t)b * TT * HH;
    __hip_bfloat16* hb = hall + (size_t)b * TT * HH;
    float xpn = (tid < HH) ? (float)xpb[tid] : 0.0f;

    int cur = 0;
    for (int t = 0; t < TT; ++t) {
        const float* hc = hbuf[cur];
        // wave-uniform broadcast reads of this wave's k-slice
        float4 h0 = *(const float4*)(hc + q * 16 + 0);
        float4 h1 = *(const float4*)(hc + q * 16 + 4);
        float4 h2 = *(const float4*)(hc + q * 16 + 8);
        float4 h3 = *(const float4*)(hc + q * 16 + 12);
        float hreg[16] = {h0.x, h0.y, h0.z, h0.w, h1.x, h1.y, h1.z, h1.w,
                          h2.x, h2.y, h2.z, h2.w, h3.x, h3.y, h3.z, h3.w};
        float a0 = 0.f, a1 = 0.f, a2 = 0.f, a3 = 0.f;
        #pragma unroll
        for (int kk = 0; kk < 16; ++kk) {
            const float hk = hreg[kk];
            a0 = fmaf(w[0][kk], hk, a0);
            a1 = fmaf(w[1][kk], hk, a1);
            a2 = fmaf(w[2][kk], hk, a2);
            a3 = fmaf(w[3][kk], hk, a3);
        }
        *(float4*)(&ps[q][g * 4]) = make_float4(a0, a1, a2, a3);

        const float xpc = xpn;
        if (tid < HH && t + 1 < TT) xpn = (float)xpb[(size_t)(t + 1) * HH + tid];
        __syncthreads();

        if (tid < HH) {
            float s = xpc;
            #pragma unroll
            for (int qq = 0; qq < 16; ++qq) s += ps[qq][tid];
            const float hn = tanh_fast(s);
            hbuf[cur ^ 1][tid] = hn;
            hb[(size_t)t * HH + tid] = __float2bfloat16(hn);
        }
        __syncthreads();
        cur ^= 1;
    }
}

// ---------------------------------------------------------------------------
extern "C" void kernel_launch(void* const* d_in, const int* in_sizes, int n_in,
                              void* d_out, int out_size, void* d_ws, size_t ws_size,
                              hipStream_t stream) {
    const float* x     = (const float*)d_in[0];   // [B][T][I]
    const float* W_in  = (const float*)d_in[1];   // [H][I]
    const float* b_in  = (const float*)d_in[2];   // [H]
    const float* W_out = (const float*)d_in[3];   // [O][H]
    const float* b_out = (const float*)d_in[4];   // [O]
    const float* u_raw = (const float*)d_in[5];   // [M][H], M=256
    const float* sig   = (const float*)d_in[6];   // [H]
    const float* v_raw = (const float*)d_in[7];   // [M][H]
    float* out = (float*)d_out;                   // [B][T][O]

    char* ws = (char*)d_ws;
    size_t off = 0;
    auto alloc = [&](size_t bytes) -> void* {
        void* p = (void*)(ws + off);
        off += (bytes + 255) & ~((size_t)255);
        return p;
    };
    float* u_eff  = (float*)alloc((size_t)HH * HH * 4);
    float* v_eff  = (float*)alloc((size_t)HH * HH * 4);
    float* beta_u = (float*)alloc((size_t)HH * 4);
    float* beta_v = (float*)alloc((size_t)HH * 4);
    float* Ucol   = (float*)alloc((size_t)HH * HH * 4);
    float* Vrow   = (float*)alloc((size_t)HH * HH * 4);
    float* Wm     = (float*)alloc((size_t)HH * HH * 4);
    __hip_bfloat16* xp   = (__hip_bfloat16*)alloc((size_t)BB * TT * HH * 2);
    __hip_bfloat16* hall = (__hip_bfloat16*)alloc((size_t)BB * TT * HH * 2);
    // total ws use: ~135.5 MB; if ws_size is smaller this faults visibly.
    (void)ws_size; (void)in_sizes; (void)n_in; (void)out_size;

    prep_kernel<<<2 * HH, 64, 0, stream>>>(u_raw, v_raw, u_eff, v_eff, beta_u, beta_v);
    hh_kernel<<<(2 * HH) / 4, 256, 0, stream>>>(u_eff, v_eff, beta_u, beta_v, Ucol, Vrow);
    w_kernel<<<HH, HH, 0, stream>>>(Ucol, Vrow, sig, Wm);
    gemm_bias<float, __hip_bfloat16>
        <<<dim3((BB * TT) / 64, HH / 64), 256, 0, stream>>>(x, W_in, b_in, xp, BB * TT, HH, II);
    recur_kernel<<<BB, 1024, 0, stream>>>(Wm, xp, hall);
    gemm_bias<__hip_bfloat16, float>
        <<<dim3((BB * TT) / 64, OO / 64), 256, 0, stream>>>(hall, W_out, b_out, out, BB * TT, OO, HH);
}